// Round 1
// baseline (64.456 us; speedup 1.0000x reference)
//
#include <hip/hip_runtime.h>
#include <hip/hip_bf16.h>

#define DIM 384
#define RED 16
#define PAIR 128
#define B 2
#define M 512
#define EPSV 1e-5f

// ---------------------------------------------------------------------------
// K1: per (b,m) row: LayerNorm(384) -> xr[16] = xn @ w_red + b_red
//     -> T[16][128] : T[i][p] = sum_j xr[j] * w_out[(i*16+j)*128 + p]
// grid = B*M = 1024 blocks, block = 128 threads
// ---------------------------------------------------------------------------
__global__ __launch_bounds__(128) void opm_k1(
    const float* __restrict__ x, const float* __restrict__ g,
    const float* __restrict__ be, const float* __restrict__ w_red,
    const float* __restrict__ b_red, const float* __restrict__ w_out,
    float* __restrict__ xr_out, float* __restrict__ T_out) {
  const int row = blockIdx.x;           // b*M + m
  const int tid = threadIdx.x;          // 0..127
  const float* xrow = x + (size_t)row * DIM;

  __shared__ float xn[DIM];
  __shared__ float xr_s[RED];
  __shared__ float rs[2][2];
  __shared__ float psum[8][RED];

  // load 3 elems/thread
  float v0 = xrow[tid];
  float v1 = xrow[tid + 128];
  float v2 = xrow[tid + 256];
  float s  = v0 + v1 + v2;
  float sq = v0 * v0 + v1 * v1 + v2 * v2;
  // wave reduce (wave = 64 lanes)
  #pragma unroll
  for (int off = 32; off > 0; off >>= 1) {
    s  += __shfl_down(s, off);
    sq += __shfl_down(sq, off);
  }
  if ((tid & 63) == 0) { rs[0][tid >> 6] = s; rs[1][tid >> 6] = sq; }
  __syncthreads();
  const float mean = (rs[0][0] + rs[0][1]) * (1.0f / DIM);
  const float var  = (rs[1][0] + rs[1][1]) * (1.0f / DIM) - mean * mean;
  const float rstd = rsqrtf(var + EPSV);

  xn[tid]       = (v0 - mean) * rstd * g[tid]       + be[tid];
  xn[tid + 128] = (v1 - mean) * rstd * g[tid + 128] + be[tid + 128];
  xn[tid + 256] = (v2 - mean) * rstd * g[tid + 256] + be[tid + 256];
  __syncthreads();

  // xr: 16 outputs, 8 partial-sums each over 48 dims
  {
    const int r = tid & 15;
    const int part = tid >> 4;  // 0..7
    float ps = 0.0f;
    const int d0 = part * 48;
    #pragma unroll 8
    for (int d = d0; d < d0 + 48; ++d) ps += xn[d] * w_red[d * RED + r];
    psum[part][r] = ps;
  }
  __syncthreads();
  if (tid < RED) {
    float v = b_red[tid];
    #pragma unroll
    for (int q = 0; q < 8; ++q) v += psum[q][tid];
    xr_s[tid] = v;
    xr_out[(size_t)row * RED + tid] = v;
  }
  __syncthreads();

  // T row: thread p handles all 16 i
  {
    const int p = tid;  // 0..127
    const float* W = w_out + p;
    float* Trow = T_out + (size_t)row * RED * PAIR + p;
    #pragma unroll
    for (int i = 0; i < RED; ++i) {
      float acc = 0.0f;
      #pragma unroll
      for (int j = 0; j < RED; ++j) acc += xr_s[j] * W[(i * RED + j) * PAIR];
      Trow[i * PAIR] = acc;
    }
  }
}

// ---------------------------------------------------------------------------
// K2: out[b,m,n,p] = b_out[p] + sum_i xr[b,m,i] * T[b,n,i,p]
// block = 256 threads: p = tid&127, half = tid>>7 -> two n per thread.
// block tile: 16 m  x  4 n  x  128 p.
// grid = B * (M/16) * (M/4) = 2*32*128 = 8192
// ---------------------------------------------------------------------------
__global__ __launch_bounds__(256) void opm_k2(
    const float* __restrict__ xr, const float* __restrict__ T,
    const float* __restrict__ b_out, float* __restrict__ out) {
  const int nc  = blockIdx.x & 127;          // n-chunk
  const int mt  = (blockIdx.x >> 7) & 31;    // m-tile
  const int b   = blockIdx.x >> 12;
  const int tid = threadIdx.x;
  const int p    = tid & 127;
  const int half = tid >> 7;                 // 0 or 1

  __shared__ float a_s[16 * RED];            // xr m-tile: 16 rows x 16

  a_s[tid] = xr[((size_t)(b * M + mt * 16)) * RED + tid];

  const float bias = b_out[p];
  const int n_base = nc * 4 + half * 2;      // this thread's first n

  // T fragments for n_base and n_base+1: 16 regs each
  float t0[RED], t1[RED];
  const float* Tb = T + ((size_t)(b * M + n_base) * RED) * PAIR + p;
  #pragma unroll
  for (int i = 0; i < RED; ++i) {
    t0[i] = Tb[i * PAIR];
    t1[i] = Tb[RED * PAIR + i * PAIR];
  }
  __syncthreads();

  float* outp = out + (((size_t)(b * M + mt * 16) * M + n_base) * PAIR) + p;
  #pragma unroll 4
  for (int m = 0; m < 16; ++m) {
    const float4 a0 = *reinterpret_cast<const float4*>(&a_s[m * RED + 0]);
    const float4 a1 = *reinterpret_cast<const float4*>(&a_s[m * RED + 4]);
    const float4 a2 = *reinterpret_cast<const float4*>(&a_s[m * RED + 8]);
    const float4 a3 = *reinterpret_cast<const float4*>(&a_s[m * RED + 12]);
    float acc0 = bias, acc1 = bias;
    acc0 += a0.x * t0[0];  acc1 += a0.x * t1[0];
    acc0 += a0.y * t0[1];  acc1 += a0.y * t1[1];
    acc0 += a0.z * t0[2];  acc1 += a0.z * t1[2];
    acc0 += a0.w * t0[3];  acc1 += a0.w * t1[3];
    acc0 += a1.x * t0[4];  acc1 += a1.x * t1[4];
    acc0 += a1.y * t0[5];  acc1 += a1.y * t1[5];
    acc0 += a1.z * t0[6];  acc1 += a1.z * t1[6];
    acc0 += a1.w * t0[7];  acc1 += a1.w * t1[7];
    acc0 += a2.x * t0[8];  acc1 += a2.x * t1[8];
    acc0 += a2.y * t0[9];  acc1 += a2.y * t1[9];
    acc0 += a2.z * t0[10]; acc1 += a2.z * t1[10];
    acc0 += a2.w * t0[11]; acc1 += a2.w * t1[11];
    acc0 += a3.x * t0[12]; acc1 += a3.x * t1[12];
    acc0 += a3.y * t0[13]; acc1 += a3.y * t1[13];
    acc0 += a3.z * t0[14]; acc1 += a3.z * t1[14];
    acc0 += a3.w * t0[15]; acc1 += a3.w * t1[15];
    outp[0]   = acc0;
    outp[PAIR] = acc1;          // n+1
    outp += (size_t)M * PAIR;   // next m
  }
}

extern "C" void kernel_launch(void* const* d_in, const int* in_sizes, int n_in,
                              void* d_out, int out_size, void* d_ws, size_t ws_size,
                              hipStream_t stream) {
  const float* x       = (const float*)d_in[0];
  const float* ln_g    = (const float*)d_in[1];
  const float* ln_b    = (const float*)d_in[2];
  const float* w_red   = (const float*)d_in[3];
  const float* b_red   = (const float*)d_in[4];
  const float* w_out   = (const float*)d_in[5];
  const float* b_out   = (const float*)d_in[6];
  float* out = (float*)d_out;

  float* xr = (float*)d_ws;                      // B*M*RED   = 16384 floats (64 KB)
  float* T  = xr + (size_t)B * M * RED;          // B*M*RED*PAIR = 2 MiFloats (8 MB)

  opm_k1<<<B * M, 128, 0, stream>>>(x, ln_g, ln_b, w_red, b_red, w_out, xr, T);
  opm_k2<<<B * (M / 16) * (M / 4), 256, 0, stream>>>(xr, T, b_out, out);
}